// Round 5
// baseline (268.976 us; speedup 1.0000x reference)
//
#include <hip/hip_runtime.h>
#include <hip/hip_bf16.h>

// B=256, x:[B,80,14,14] f32, w1:[512,80], b1:[512], w2:[512,512], b2:[512],
// w3:[512,4,14,14], fc_w:[80,2048], fc_b:[80] -> out:[B,80] f32.
// h2 = (w2@w1) x + (w2@b1+b2); bias folded as k-channel 80 (x col 80 = 1.0).
#define CIN 80
#define NSP 196
#define HWP 208        // hw padded 196->208 (13 n-tiles of 16)
#define KP  96         // k padded 80(+bias)->96 (3 MFMA k-steps of 32)

typedef __attribute__((ext_vector_type(8))) short  short8;
typedef __attribute__((ext_vector_type(4))) float  floatx4;
typedef __attribute__((ext_vector_type(4))) unsigned short ushort4v;

static __device__ __forceinline__ unsigned short f2b(float f) {
    __hip_bfloat16 h = __float2bfloat16(f);
    return *(unsigned short*)&h;
}
static __device__ __forceinline__ float b2f(unsigned short u) {
    unsigned int x = ((unsigned int)u) << 16;
    float f; __builtin_memcpy(&f, &x, 4); return f;
}

// ---- kW: Wcbf[512][96] bf16 = (w2@w1 | w2@b1+b2 | 0-pad). One thread/entry. -
__global__ __launch_bounds__(256) void kW(
    const float* __restrict__ w1, const float* __restrict__ b1,
    const float* __restrict__ w2, const float* __restrict__ b2,
    unsigned short* __restrict__ Wcbf)
{
    const int idx = blockIdx.x * 256 + threadIdx.x;    // 192 blocks -> 512*96
    const int o = idx / KP, c = idx - o * KP;
    const float* __restrict__ w2r = w2 + (size_t)o * 512;
    const int cc = (c < CIN) ? c : 0;
    const bool isw = (c < CIN);
    float acc = 0.f;
    #pragma unroll 8
    for (int m = 0; m < 512; ++m) {
        const float xv = isw ? w1[m * CIN + cc] : b1[m];  // per-lane addr select
        acc = fmaf(w2r[m], xv, acc);
    }
    float r = 0.f;
    if (c < CIN) r = acc;
    else if (c == CIN) r = acc + b2[o];
    Wcbf[idx] = f2b(r);
}

// ---- kX: x [b][80][196] f32 -> xbf [b][208][96] bf16 (col80=1, pads=0) ------
__global__ __launch_bounds__(256) void kX(
    const float* __restrict__ x, unsigned short* __restrict__ xbf)
{
    __shared__ float tile[80 * 53];   // read k-major coalesced, write hw-major
    const int r = blockIdx.x;         // 1024 = 256 b x 4 hw-quarters
    const int b = r >> 2, qt = r & 3, hw0 = qt * 52;
    const int t = threadIdx.x;
    for (int idx = t; idx < 80 * 52; idx += 256) {
        const int k = idx / 52, hl = idx - k * 52;
        const int hw = hw0 + hl;
        tile[k * 53 + hl] = (hw < NSP) ? x[(size_t)b * CIN * NSP + k * NSP + hw] : 0.f;
    }
    __syncthreads();
    unsigned short* __restrict__ ob = xbf + (size_t)b * HWP * KP;
    for (int idx = t; idx < 52 * KP; idx += 256) {
        const int hl = idx / KP, k = idx - hl * KP;
        const int hw = hw0 + hl;
        float f = 0.f;
        if (hw < NSP) {
            if (k < CIN) f = tile[k * 53 + hl];
            else if (k == CIN) f = 1.f;            // bias channel
        }
        ob[(size_t)hw * KP + k] = f2b(f);
    }
}

// ---- kT: w3->w3tb bf16 [g][208][4]; fc_w->fctb bf16 [2048][80]; out=fc_b ----
__global__ __launch_bounds__(256) void kT(
    const float* __restrict__ w3, const float* __restrict__ fc_w,
    const float* __restrict__ fc_b,
    unsigned short* __restrict__ w3tb, unsigned short* __restrict__ fctb,
    float* __restrict__ out)
{
    const int blk = blockIdx.x, t = threadIdx.x;
    if (blk < 512) {
        const int g = blk;
        if (t < HWP) {
            ushort4v v;
            #pragma unroll
            for (int o = 0; o < 4; ++o)
                v[o] = f2b((t < NSP) ? w3[(size_t)g * 4 * NSP + o * NSP + t] : 0.f);
            *(ushort4v*)(w3tb + ((size_t)g * HWP + t) * 4) = v;
        }
    } else if (blk < 576) {
        const int base = (blk - 512) * 2560;       // 64 blocks -> 2048*80
        for (int i = t; i < 2560; i += 256) {
            const int idx = base + i;
            const int k = idx / CIN, l = idx - k * CIN;
            fctb[idx] = f2b(fc_w[(size_t)l * 2048 + k]);
        }
    } else {
        const int base = (blk - 576) * 1280;       // 16 blocks -> 256*80
        for (int i = t; i < 1280; i += 256) {
            const int idx = base + i;
            out[idx] = fc_b[idx % CIN];
        }
    }
}

// ---- kM: fused GEMM + conv3 + relu + fc-partial -----------------------------
// block = (2 batches, 64-group chunk); wave = 16 groups. R3 locality + R4 regs.
__global__ __launch_bounds__(256, 4) void kM(
    const unsigned short* __restrict__ xbf, const unsigned short* __restrict__ Wcbf,
    const unsigned short* __restrict__ w3tb, const unsigned short* __restrict__ fctb,
    float* __restrict__ out)
{
    __shared__ float gl[2 * 256];     // [bi][glocal*4+o]
    const int bp = blockIdx.x, gc = blockIdx.y;   // b fast -> gc-slice L2 reuse
    const int w = threadIdx.x >> 6, lane = threadIdx.x & 63;
    const int col = lane & 15, quad = lane >> 4;
    const int g0 = gc * 64 + w * 16;
    const int b0 = bp * 2;

    // A-frags: 16 groups x 96 k in 12 VGPRs for the whole kernel
    const unsigned short* __restrict__ ap = Wcbf + (size_t)(g0 + col) * KP + quad * 8;
    short8 A[3];
    #pragma unroll
    for (int ks = 0; ks < 3; ++ks) A[ks] = *(const short8*)(ap + ks * 32);

    float p[2][4][4];   // conv3 partials [bi][r][o]
    #pragma unroll
    for (int bi = 0; bi < 2; ++bi)
        #pragma unroll
        for (int r = 0; r < 4; ++r)
            #pragma unroll
            for (int o = 0; o < 4; ++o) p[bi][r][o] = 0.f;

    const unsigned short* __restrict__ xb0 = xbf + ((size_t)b0 * HWP + col) * KP + quad * 8;
    const unsigned short* __restrict__ wb  = w3tb + ((size_t)(g0 + quad * 4) * HWP + col) * 4;

    #pragma unroll 2
    for (int nt = 0; nt < 13; ++nt) {
        // w3 rows for this n-tile (shared across both batches), bf16 -> f32
        float wv[4][4];
        #pragma unroll
        for (int r = 0; r < 4; ++r) {
            const ushort4v u = *(const ushort4v*)(wb + ((size_t)r * HWP + nt * 16) * 4);
            wv[r][0] = b2f(u[0]); wv[r][1] = b2f(u[1]);
            wv[r][2] = b2f(u[2]); wv[r][3] = b2f(u[3]);
        }
        #pragma unroll
        for (int bi = 0; bi < 2; ++bi) {
            const unsigned short* __restrict__ xp = xb0 + ((size_t)bi * HWP + nt * 16) * KP;
            const short8 x0 = *(const short8*)(xp);
            const short8 x1 = *(const short8*)(xp + 32);
            const short8 x2 = *(const short8*)(xp + 64);
            floatx4 acc = {0.f, 0.f, 0.f, 0.f};
            acc = __builtin_amdgcn_mfma_f32_16x16x32_bf16(A[0], x0, acc, 0, 0, 0);
            acc = __builtin_amdgcn_mfma_f32_16x16x32_bf16(A[1], x1, acc, 0, 0, 0);
            acc = __builtin_amdgcn_mfma_f32_16x16x32_bf16(A[2], x2, acc, 0, 0, 0);
            // C/D: col(hw)=lane&15, row(g)=quad*4+r  [m89-verified]
            #pragma unroll
            for (int r = 0; r < 4; ++r) {
                p[bi][r][0] = fmaf(acc[r], wv[r][0], p[bi][r][0]);
                p[bi][r][1] = fmaf(acc[r], wv[r][1], p[bi][r][1]);
                p[bi][r][2] = fmaf(acc[r], wv[r][2], p[bi][r][2]);
                p[bi][r][3] = fmaf(acc[r], wv[r][3], p[bi][r][3]);
            }
        }
    }

    // reduce over 16 hw-lanes, relu, stash in LDS
    #pragma unroll
    for (int bi = 0; bi < 2; ++bi)
        #pragma unroll
        for (int r = 0; r < 4; ++r) {
            float q0 = p[bi][r][0], q1 = p[bi][r][1], q2 = p[bi][r][2], q3 = p[bi][r][3];
            #pragma unroll
            for (int s = 8; s >= 1; s >>= 1) {
                q0 += __shfl_down(q0, s, 16);
                q1 += __shfl_down(q1, s, 16);
                q2 += __shfl_down(q2, s, 16);
                q3 += __shfl_down(q3, s, 16);
            }
            if (col == 0) {
                const int glocal = w * 16 + quad * 4 + r;
                floatx4 ov = {fmaxf(q0, 0.f), fmaxf(q1, 0.f), fmaxf(q2, 0.f), fmaxf(q3, 0.f)};
                *(floatx4*)(gl + bi * 256 + glocal * 4) = ov;
            }
        }
    __syncthreads();

    // fc partial over this block's 256 k-cols, both batches
    const int t = threadIdx.x;
    if (t < 160) {
        const int l = t % CIN, half = t / CIN;
        const unsigned short* __restrict__ fr = fctb + (size_t)(gc * 256 + half * 128) * CIN + l;
        const float* __restrict__ gp = gl + half * 128;
        float s0 = 0.f, s1 = 0.f;
        #pragma unroll 4
        for (int kk = 0; kk < 128; ++kk) {
            const float fv = b2f(fr[(size_t)kk * CIN]);
            s0 = fmaf(gp[kk      ], fv, s0);
            s1 = fmaf(gp[kk + 256], fv, s1);
        }
        atomicAdd(out + (b0 + 0) * CIN + l, s0);
        atomicAdd(out + (b0 + 1) * CIN + l, s1);
    }
}

extern "C" void kernel_launch(void* const* d_in, const int* in_sizes, int n_in,
                              void* d_out, int out_size, void* d_ws, size_t ws_size,
                              hipStream_t stream) {
    const float* x    = (const float*)d_in[0];
    const float* w1   = (const float*)d_in[1];
    const float* b1   = (const float*)d_in[2];
    const float* w2   = (const float*)d_in[3];
    const float* b2   = (const float*)d_in[4];
    const float* w3   = (const float*)d_in[5];
    const float* fc_w = (const float*)d_in[6];
    const float* fc_b = (const float*)d_in[7];
    float* out = (float*)d_out;

    const int B = in_sizes[0] / (CIN * NSP);   // 256

    // workspace: xbf | Wcbf | w3tb | fctb  (~11.5 MB)
    char* ws = (char*)d_ws;
    unsigned short* xbf  = (unsigned short*)ws;                 // B*208*96*2
    size_t off = (size_t)B * HWP * KP * 2;
    unsigned short* Wcbf = (unsigned short*)(ws + off); off += 512 * KP * 2;
    unsigned short* w3tb = (unsigned short*)(ws + off); off += (size_t)512 * HWP * 4 * 2;
    unsigned short* fctb = (unsigned short*)(ws + off);         // 2048*80*2

    kW<<<192, 256, 0, stream>>>(w1, b1, w2, b2, Wcbf);
    kX<<<B * 4, 256, 0, stream>>>(x, xbf);
    kT<<<592, 256, 0, stream>>>(w3, fc_w, fc_b, w3tb, fctb, out);
    kM<<<dim3(B / 2, 8), 256, 0, stream>>>(xbf, Wcbf, w3tb, fctb, out);
}

// Round 6
// 216.478 us; speedup vs baseline: 1.2425x; 1.2425x over previous
//
#include <hip/hip_runtime.h>
#include <hip/hip_bf16.h>

// B=256, x:[B,80,14,14] f32, w1:[512,80], b1:[512], w2:[512,512], b2:[512],
// w3:[512,4,14,14], fc_w:[80,2048], fc_b:[80] -> out:[B,80] f32.
// h2 = (w2@w1) x + (w2@b1+b2); bias folded as k-channel 80 (x col 80 = 1.0).
#define CIN 80
#define NSP 196
#define HWP 208        // hw padded 196->208 (13 n-tiles of 16)
#define KP  96         // W rows: 80(+bias)->96 (3 MFMA k-steps of 32)
#define KX  104        // x rows: 96 + 8 pad so LDS row stride = 52 dwords (2-way banks)

#define NBA 192        // Wc compose: 192*256 = 512*96 threads, 1/entry
#define NBB 1024       // x-prep: 256 b x 4 hw-quarters
#define NBC 512        // w3 transpose (f32)
#define NBD 64         // fc_w transpose (f32)
#define NBE 16         // out init

typedef __attribute__((ext_vector_type(8))) short  short8;
typedef __attribute__((ext_vector_type(4))) float  floatx4;
typedef __attribute__((ext_vector_type(4))) unsigned short ushort4v;

static __device__ __forceinline__ unsigned short f2b(float f) {
    __hip_bfloat16 h = __float2bfloat16(f);
    return *(unsigned short*)&h;
}

// ---- kPre: all prep in ONE dispatch (roles independent, no atomics) ---------
__global__ __launch_bounds__(256) void kPre(
    const float* __restrict__ x,  const float* __restrict__ w1,
    const float* __restrict__ b1, const float* __restrict__ w2,
    const float* __restrict__ b2, const float* __restrict__ w3,
    const float* __restrict__ fc_w, const float* __restrict__ fc_b,
    unsigned short* __restrict__ Wcbf, unsigned short* __restrict__ xbf,
    float* __restrict__ w3t, float* __restrict__ fct, float* __restrict__ out)
{
    __shared__ float tile[80 * 53];
    const int blk = blockIdx.x, t = threadIdx.x;

    if (blk < NBA) {
        // Wcbf[o][96] bf16: c<80 -> (w2@w1)[o][c]; c==80 -> w2@b1+b2; else 0
        const int idx = blk * 256 + t;
        const int o = idx / KP, c = idx - o * KP;
        const float* __restrict__ w2r = w2 + (size_t)o * 512;
        const int cc = (c < CIN) ? c : 0;
        const bool isw = (c < CIN);
        float acc = 0.f;
        #pragma unroll 8
        for (int m = 0; m < 512; ++m) {
            const float xv = isw ? w1[m * CIN + cc] : b1[m];
            acc = fmaf(w2r[m], xv, acc);
        }
        float r = 0.f;
        if (c < CIN) r = acc;
        else if (c == CIN) r = acc + b2[o];
        Wcbf[idx] = f2b(r);
    } else if (blk < NBA + NBB) {
        // x [b][80][196] f32 -> xbf [b][208][104] bf16 (col80=1, all pads=0)
        const int r = blk - NBA;
        const int b = r >> 2, qt = r & 3, hw0 = qt * 52;
        for (int idx = t; idx < 80 * 52; idx += 256) {
            const int k = idx / 52, hl = idx - k * 52;
            const int hw = hw0 + hl;
            tile[k * 53 + hl] = (hw < NSP) ? x[(size_t)b * CIN * NSP + k * NSP + hw] : 0.f;
        }
        __syncthreads();
        unsigned short* __restrict__ ob = xbf + (size_t)b * HWP * KX;
        for (int idx = t; idx < 52 * 26; idx += 256) {   // ushort4 stores
            const int hl = idx / 26, kq = idx - hl * 26;
            const int hw = hw0 + hl;
            ushort4v v;
            #pragma unroll
            for (int j = 0; j < 4; ++j) {
                const int k = kq * 4 + j;
                float f = 0.f;
                if (hw < NSP) {
                    if (k < CIN) f = tile[k * 53 + hl];
                    else if (k == CIN) f = 1.f;        // bias channel
                }
                v[j] = f2b(f);
            }
            *(ushort4v*)(ob + (size_t)hw * KX + kq * 4) = v;
        }
    } else if (blk < NBA + NBB + NBC) {
        // w3 [g][4][196] -> w3t [g][208][4] f32, hw zero-padded
        const int g = blk - NBA - NBB;
        if (t < HWP) {
            floatx4 v;
            #pragma unroll
            for (int o = 0; o < 4; ++o)
                v[o] = (t < NSP) ? w3[(size_t)g * 4 * NSP + o * NSP + t] : 0.f;
            *(floatx4*)(w3t + ((size_t)g * HWP + t) * 4) = v;
        }
    } else if (blk < NBA + NBB + NBC + NBD) {
        // fc_w [80][2048] -> fct [2048][80] f32
        const int base = (blk - NBA - NBB - NBC) * 2560;
        for (int i = t; i < 2560; i += 256) {
            const int idx = base + i;
            const int k = idx / CIN, l = idx - k * CIN;
            fct[idx] = fc_w[(size_t)l * 2048 + k];
        }
    } else {
        // out init = fc_b broadcast
        const int base = (blk - NBA - NBB - NBC - NBD) * 1280;
        for (int i = t; i < 1280; i += 256)
            out[base + i] = fc_b[(base + i) % CIN];
    }
}

// ---- kM: fused GEMM + conv3 + relu + fc-partial -----------------------------
// block = (b, 128-group chunk gc); 4 waves x 32 groups. x[b] staged in LDS.
// NOTE: no min-waves launch bound — R5 showed it silently spills (236 MB scratch).
__global__ __launch_bounds__(256) void kM(
    const unsigned short* __restrict__ xbf, const unsigned short* __restrict__ Wcbf,
    const float* __restrict__ w3t, const float* __restrict__ fct,
    float* __restrict__ out)
{
    __shared__ __align__(16) unsigned short xs[HWP * KX];  // 43264 B
    __shared__ float gl[512];                              // relu'd group outputs
    const int b = blockIdx.x, gc = blockIdx.y;             // b fast: good L2 reuse
    const int t = threadIdx.x;

    // stage x[b] (linear uint4 copy, coalesced)
    {
        const uint4* __restrict__ src = (const uint4*)(xbf + (size_t)b * HWP * KX);
        uint4* dst = (uint4*)xs;
        for (int i = t; i < HWP * KX / 8; i += 256) dst[i] = src[i];
    }
    __syncthreads();

    const int w = t >> 6, lane = t & 63;
    const int col = lane & 15, quad = lane >> 4;
    const int g0 = gc * 128 + w * 32;

    // A-frags: 32 groups x 96 k in 24 VGPRs (global, L2-hit, once)
    short8 A[2][3];
    #pragma unroll
    for (int mt = 0; mt < 2; ++mt) {
        const unsigned short* __restrict__ ap =
            Wcbf + (size_t)(g0 + mt * 16 + col) * KP + quad * 8;
        #pragma unroll
        for (int ks = 0; ks < 3; ++ks) A[mt][ks] = *(const short8*)(ap + ks * 32);
    }

    float p[2][4][4];   // conv3 partials [mt][r][o]
    #pragma unroll
    for (int mt = 0; mt < 2; ++mt)
        #pragma unroll
        for (int r = 0; r < 4; ++r)
            #pragma unroll
            for (int o = 0; o < 4; ++o) p[mt][r][o] = 0.f;

    const unsigned short* __restrict__ xrow = xs + col * KX + quad * 8;
    const float* __restrict__ wb = w3t + ((size_t)(g0 + quad * 4) * HWP + col) * 4;

    #pragma unroll 2
    for (int nt = 0; nt < 13; ++nt) {
        const unsigned short* __restrict__ xp = xrow + nt * 16 * KX;
        const short8 x0 = *(const short8*)(xp);
        const short8 x1 = *(const short8*)(xp + 32);
        const short8 x2 = *(const short8*)(xp + 64);
        floatx4 acc0 = {0.f, 0.f, 0.f, 0.f}, acc1 = {0.f, 0.f, 0.f, 0.f};
        acc0 = __builtin_amdgcn_mfma_f32_16x16x32_bf16(A[0][0], x0, acc0, 0, 0, 0);
        acc0 = __builtin_amdgcn_mfma_f32_16x16x32_bf16(A[0][1], x1, acc0, 0, 0, 0);
        acc0 = __builtin_amdgcn_mfma_f32_16x16x32_bf16(A[0][2], x2, acc0, 0, 0, 0);
        acc1 = __builtin_amdgcn_mfma_f32_16x16x32_bf16(A[1][0], x0, acc1, 0, 0, 0);
        acc1 = __builtin_amdgcn_mfma_f32_16x16x32_bf16(A[1][1], x1, acc1, 0, 0, 0);
        acc1 = __builtin_amdgcn_mfma_f32_16x16x32_bf16(A[1][2], x2, acc1, 0, 0, 0);
        // conv3 partials; C/D: col(hw)=lane&15, row(g)=quad*4+r  [m89-verified]
        #pragma unroll
        for (int mt = 0; mt < 2; ++mt) {
            const floatx4 av = mt ? acc1 : acc0;
            #pragma unroll
            for (int r = 0; r < 4; ++r) {
                const floatx4 wv = *(const floatx4*)(wb + ((size_t)(mt * 16 + r) * HWP + nt * 16) * 4);
                p[mt][r][0] = fmaf(av[r], wv[0], p[mt][r][0]);
                p[mt][r][1] = fmaf(av[r], wv[1], p[mt][r][1]);
                p[mt][r][2] = fmaf(av[r], wv[2], p[mt][r][2]);
                p[mt][r][3] = fmaf(av[r], wv[3], p[mt][r][3]);
            }
        }
    }

    // reduce over 16 hw-lanes, relu, stash in LDS
    #pragma unroll
    for (int mt = 0; mt < 2; ++mt)
        #pragma unroll
        for (int r = 0; r < 4; ++r) {
            float q0 = p[mt][r][0], q1 = p[mt][r][1], q2 = p[mt][r][2], q3 = p[mt][r][3];
            #pragma unroll
            for (int s = 8; s >= 1; s >>= 1) {
                q0 += __shfl_down(q0, s, 16);
                q1 += __shfl_down(q1, s, 16);
                q2 += __shfl_down(q2, s, 16);
                q3 += __shfl_down(q3, s, 16);
            }
            if (col == 0) {
                const int glocal = w * 32 + mt * 16 + quad * 4 + r;
                floatx4 ov = {fmaxf(q0, 0.f), fmaxf(q1, 0.f), fmaxf(q2, 0.f), fmaxf(q3, 0.f)};
                *(floatx4*)(gl + glocal * 4) = ov;
            }
        }
    __syncthreads();

    // fc partial over this block's 512 k-cols (k = gc*512 + klocal)
    if (t < 160) {
        const int l = t % CIN, half = t / CIN;
        const float* __restrict__ fr = fct + (size_t)(gc * 512 + half * 256) * CIN + l;
        const float* __restrict__ gp = gl + half * 256;
        float s = 0.f;
        #pragma unroll 4
        for (int kk = 0; kk < 256; ++kk)
            s = fmaf(gp[kk], fr[(size_t)kk * CIN], s);
        atomicAdd(out + b * CIN + l, s);             // out pre-set to fc_b by kPre
    }
}

extern "C" void kernel_launch(void* const* d_in, const int* in_sizes, int n_in,
                              void* d_out, int out_size, void* d_ws, size_t ws_size,
                              hipStream_t stream) {
    const float* x    = (const float*)d_in[0];
    const float* w1   = (const float*)d_in[1];
    const float* b1   = (const float*)d_in[2];
    const float* w2   = (const float*)d_in[3];
    const float* b2   = (const float*)d_in[4];
    const float* w3   = (const float*)d_in[5];
    const float* fc_w = (const float*)d_in[6];
    const float* fc_b = (const float*)d_in[7];
    float* out = (float*)d_out;

    const int B = in_sizes[0] / (CIN * NSP);   // 256

    // workspace: xbf | Wcbf | w3t | fct  (~13.5 MB)
    char* ws = (char*)d_ws;
    unsigned short* xbf  = (unsigned short*)ws;                 // B*208*104*2
    size_t off = (size_t)B * HWP * KX * 2;
    unsigned short* Wcbf = (unsigned short*)(ws + off); off += 512 * KP * 2;
    float* w3t = (float*)(ws + off);  off += (size_t)512 * HWP * 4 * 4;
    float* fct = (float*)(ws + off);                            // 2048*80*4

    kPre<<<NBA + NBB + NBC + NBD + NBE, 256, 0, stream>>>(
        x, w1, b1, w2, b2, w3, fc_w, fc_b, Wcbf, xbf, w3t, fct, out);
    kM<<<dim3(B, 4), 256, 0, stream>>>(xbf, Wcbf, w3t, fct, out);
}

// Round 7
// 132.991 us; speedup vs baseline: 2.0225x; 1.6278x over previous
//
#include <hip/hip_runtime.h>
#include <hip/hip_bf16.h>

// B=256, x:[B,80,14,14] f32, w1:[512,80], b1:[512], w2:[512,512], b2:[512],
// w3:[512,4,14,14], fc_w:[80,2048], fc_b:[80] -> out:[B,80] f32.
// h2 = (w2@w1) x + (w2@b1+b2); bias folded as k-channel 80 (x col 80 = 1.0).
#define CIN 80
#define NSP 196
#define HWP 208        // hw padded 196->208 (13 n-tiles of 16)
#define KP  96         // k padded 80(+bias)->96 (3 MFMA k-steps of 32)

#define NBA 4096       // Wc k-split: 128 o-quads x 32 k-chunks, 16 MAC/thread
#define NBB 1024       // x-prep: 256 b x 4 hw-quarters
#define NBC 512        // w3 -> bf16 transpose
#define NBD 64         // fc_w -> bf16 transpose
#define NBE 16         // out init

typedef __attribute__((ext_vector_type(8))) short  short8;
typedef __attribute__((ext_vector_type(4))) float  floatx4;
typedef __attribute__((ext_vector_type(4))) unsigned short ushort4v;

static __device__ __forceinline__ unsigned short f2b(float f) {
    __hip_bfloat16 h = __float2bfloat16(f);
    return *(unsigned short*)&h;
}
static __device__ __forceinline__ float b2f(unsigned short u) {
    unsigned int x = ((unsigned int)u) << 16;
    float f; __builtin_memcpy(&f, &x, 4); return f;
}

// ---- kPre: all prep in ONE dispatch. Wc via wide k-split + atomics ----------
__global__ __launch_bounds__(384) void kPre(
    const float* __restrict__ x,  const float* __restrict__ w1,
    const float* __restrict__ b1, const float* __restrict__ w2,
    const float* __restrict__ b2, const float* __restrict__ w3,
    const float* __restrict__ fc_w, const float* __restrict__ fc_b,
    float* __restrict__ Wcf, unsigned short* __restrict__ xbf,
    unsigned short* __restrict__ w3tb, unsigned short* __restrict__ fctb,
    float* __restrict__ out)
{
    __shared__ float tile[80 * 53];
    const int blk = blockIdx.x, t = threadIdx.x;

    if (blk < NBA) {
        // Wcf[o][96] f32 += w2[o][m0:m0+16] @ (w1|b1)[m0:m0+16][lc]
        const int o4 = blk >> 5, kc = blk & 31;
        const int lc = t % 96, oi = t / 96;
        const int o = o4 * 4 + oi;
        const int m0 = kc * 16;
        if (lc <= CIN) {
            const float* __restrict__ w2p = w2 + (size_t)o * 512 + m0;
            float part = 0.f;
            if (lc < CIN) {
                const float* __restrict__ w1p = w1 + (size_t)m0 * CIN + lc;
                #pragma unroll
                for (int i = 0; i < 16; ++i)
                    part = fmaf(w2p[i], w1p[(size_t)i * CIN], part);
            } else {
                #pragma unroll
                for (int i = 0; i < 16; ++i)
                    part = fmaf(w2p[i], b1[m0 + i], part);
                if (kc == 31) part += b2[o];
            }
            atomicAdd(Wcf + o * KP + lc, part);   // cols 81..95 stay memset-0
        }
    } else if (blk < NBA + NBB) {
        // x [b][80][196] f32 -> xbf [b][208][96] bf16 (col80=1, all pads=0)
        const int r = blk - NBA;
        const int b = r >> 2, qt = r & 3, hw0 = qt * 52;
        for (int idx = t; idx < 80 * 52; idx += 384) {
            const int k = idx / 52, hl = idx - k * 52;
            const int hw = hw0 + hl;
            tile[k * 53 + hl] = (hw < NSP) ? x[(size_t)b * CIN * NSP + k * NSP + hw] : 0.f;
        }
        __syncthreads();
        unsigned short* __restrict__ ob = xbf + (size_t)b * HWP * KP;
        for (int idx = t; idx < 52 * 24; idx += 384) {   // 24 ushort4 per row
            const int hl = idx / 24, kq = idx - hl * 24;
            const int hw = hw0 + hl;
            ushort4v v;
            #pragma unroll
            for (int j = 0; j < 4; ++j) {
                const int k = kq * 4 + j;
                float f = 0.f;
                if (hw < NSP) {
                    if (k < CIN) f = tile[k * 53 + hl];
                    else if (k == CIN) f = 1.f;        // bias channel
                }
                v[j] = f2b(f);
            }
            *(ushort4v*)(ob + (size_t)hw * KP + kq * 4) = v;
        }
    } else if (blk < NBA + NBB + NBC) {
        // w3 [g][4][196] -> w3tb [g][208][4] bf16, hw zero-padded
        const int g = blk - NBA - NBB;
        if (t < HWP) {
            ushort4v v;
            #pragma unroll
            for (int o = 0; o < 4; ++o)
                v[o] = f2b((t < NSP) ? w3[(size_t)g * 4 * NSP + o * NSP + t] : 0.f);
            *(ushort4v*)(w3tb + ((size_t)g * HWP + t) * 4) = v;
        }
    } else if (blk < NBA + NBB + NBC + NBD) {
        // fc_w [80][2048] -> fctb [2048][80] bf16
        const int base = (blk - NBA - NBB - NBC) * 2560;
        for (int i = t; i < 2560; i += 384) {
            const int idx = base + i;
            const int k = idx / CIN, l = idx - k * CIN;
            fctb[idx] = f2b(fc_w[(size_t)l * 2048 + k]);
        }
    } else {
        // out init = fc_b broadcast
        const int base = (blk - NBA - NBB - NBC - NBD) * 1280;
        for (int i = t; i < 1280; i += 384) {
            const int idx = base + i;
            out[idx] = fc_b[idx - (idx / CIN) * CIN];
        }
    }
}

// ---- kM: fused GEMM + conv3 + relu + fc-partial -----------------------------
// block = (2 batches, 64-group chunk); wave = 16 groups. No x-LDS (R3-style),
// unroll 1 pins VGPRs (R4/R6 lesson: hoisting -> 252 regs -> 1 block/CU).
__global__ __launch_bounds__(256) void kM(
    const unsigned short* __restrict__ xbf, const float* __restrict__ Wcf,
    const unsigned short* __restrict__ w3tb, const unsigned short* __restrict__ fctb,
    float* __restrict__ out)
{
    __shared__ float gl[2 * 256];     // [bi][glocal*4+o]
    const int bp = blockIdx.x, gc = blockIdx.y;
    const int t = threadIdx.x;
    const int w = t >> 6, lane = t & 63;
    const int col = lane & 15, quad = lane >> 4;
    const int g0 = gc * 64 + w * 16;
    const int b0 = bp * 2;

    // A-frags: 16 groups x 96 k; load f32 Wc, convert to bf16 (12 VGPRs live)
    short8 A[3];
    {
        const float* __restrict__ ap = Wcf + (size_t)(g0 + col) * KP + quad * 8;
        #pragma unroll
        for (int ks = 0; ks < 3; ++ks) {
            const floatx4 lo = *(const floatx4*)(ap + ks * 32);
            const floatx4 hi = *(const floatx4*)(ap + ks * 32 + 4);
            short8 s;
            #pragma unroll
            for (int j = 0; j < 4; ++j) {
                s[j]     = (short)f2b(lo[j]);
                s[4 + j] = (short)f2b(hi[j]);
            }
            A[ks] = s;
        }
    }

    float p[2][4][4];   // conv3 partials [bi][r][o]
    #pragma unroll
    for (int bi = 0; bi < 2; ++bi)
        #pragma unroll
        for (int r = 0; r < 4; ++r)
            #pragma unroll
            for (int o = 0; o < 4; ++o) p[bi][r][o] = 0.f;

    const unsigned short* __restrict__ xb =
        xbf + ((size_t)b0 * HWP + col) * KP + quad * 8;
    const unsigned short* __restrict__ wb =
        w3tb + ((size_t)(g0 + quad * 4) * HWP + col) * 4;

    #pragma unroll 1
    for (int nt = 0; nt < 13; ++nt) {
        // w3 rows (bf16, shared by both batches)
        float wv[4][4];
        #pragma unroll
        for (int r = 0; r < 4; ++r) {
            const ushort4v u = *(const ushort4v*)(wb + ((size_t)r * HWP + nt * 16) * 4);
            wv[r][0] = b2f(u[0]); wv[r][1] = b2f(u[1]);
            wv[r][2] = b2f(u[2]); wv[r][3] = b2f(u[3]);
        }
        #pragma unroll
        for (int bi = 0; bi < 2; ++bi) {
            const unsigned short* __restrict__ xp = xb + ((size_t)bi * HWP + nt * 16) * KP;
            const short8 x0 = *(const short8*)(xp);
            const short8 x1 = *(const short8*)(xp + 32);
            const short8 x2 = *(const short8*)(xp + 64);
            floatx4 acc = {0.f, 0.f, 0.f, 0.f};
            acc = __builtin_amdgcn_mfma_f32_16x16x32_bf16(A[0], x0, acc, 0, 0, 0);
            acc = __builtin_amdgcn_mfma_f32_16x16x32_bf16(A[1], x1, acc, 0, 0, 0);
            acc = __builtin_amdgcn_mfma_f32_16x16x32_bf16(A[2], x2, acc, 0, 0, 0);
            // C/D: col(hw)=lane&15, row(g)=quad*4+r  [m89-verified]
            #pragma unroll
            for (int r = 0; r < 4; ++r) {
                p[bi][r][0] = fmaf(acc[r], wv[r][0], p[bi][r][0]);
                p[bi][r][1] = fmaf(acc[r], wv[r][1], p[bi][r][1]);
                p[bi][r][2] = fmaf(acc[r], wv[r][2], p[bi][r][2]);
                p[bi][r][3] = fmaf(acc[r], wv[r][3], p[bi][r][3]);
            }
        }
    }

    // reduce over 16 hw-lanes, relu, stash in LDS
    #pragma unroll
    for (int bi = 0; bi < 2; ++bi)
        #pragma unroll
        for (int r = 0; r < 4; ++r) {
            float q0 = p[bi][r][0], q1 = p[bi][r][1], q2 = p[bi][r][2], q3 = p[bi][r][3];
            #pragma unroll
            for (int s = 8; s >= 1; s >>= 1) {
                q0 += __shfl_down(q0, s, 16);
                q1 += __shfl_down(q1, s, 16);
                q2 += __shfl_down(q2, s, 16);
                q3 += __shfl_down(q3, s, 16);
            }
            if (col == 0) {
                const int glocal = w * 16 + quad * 4 + r;
                floatx4 ov = {fmaxf(q0, 0.f), fmaxf(q1, 0.f), fmaxf(q2, 0.f), fmaxf(q3, 0.f)};
                *(floatx4*)(gl + bi * 256 + glocal * 4) = ov;
            }
        }
    __syncthreads();

    // fc partial over this block's 256 k-cols (k = gc*256 + klocal), 2 batches
    if (t < 160) {
        const int l = t % CIN, half = t / CIN;
        const unsigned short* __restrict__ fr =
            fctb + (size_t)(gc * 256 + half * 128) * CIN + l;
        const float* __restrict__ gp = gl + half * 128;
        float s0 = 0.f, s1 = 0.f;
        #pragma unroll 4
        for (int kk = 0; kk < 128; ++kk) {
            const float fv = b2f(fr[(size_t)kk * CIN]);
            s0 = fmaf(gp[kk      ], fv, s0);
            s1 = fmaf(gp[kk + 256], fv, s1);
        }
        atomicAdd(out + (b0 + 0) * CIN + l, s0);
        atomicAdd(out + (b0 + 1) * CIN + l, s1);
    }
}

extern "C" void kernel_launch(void* const* d_in, const int* in_sizes, int n_in,
                              void* d_out, int out_size, void* d_ws, size_t ws_size,
                              hipStream_t stream) {
    const float* x    = (const float*)d_in[0];
    const float* w1   = (const float*)d_in[1];
    const float* b1   = (const float*)d_in[2];
    const float* w2   = (const float*)d_in[3];
    const float* b2   = (const float*)d_in[4];
    const float* w3   = (const float*)d_in[5];
    const float* fc_w = (const float*)d_in[6];
    const float* fc_b = (const float*)d_in[7];
    float* out = (float*)d_out;

    const int B = in_sizes[0] / (CIN * NSP);   // 256

    // workspace: xbf | Wcf | w3tb | fctb  (~11.6 MB)
    char* ws = (char*)d_ws;
    unsigned short* xbf = (unsigned short*)ws;                  // B*208*96*2
    size_t off = (size_t)B * HWP * KP * 2;
    float* Wcf = (float*)(ws + off);                   off += 512 * KP * 4;
    unsigned short* w3tb = (unsigned short*)(ws + off); off += (size_t)512 * HWP * 4 * 2;
    unsigned short* fctb = (unsigned short*)(ws + off);         // 2048*80*2

    hipMemsetAsync(Wcf, 0, 512 * KP * 4, stream);
    kPre<<<NBA + NBB + NBC + NBD + NBE, 384, 0, stream>>>(
        x, w1, b1, w2, b2, w3, fc_w, fc_b, Wcf, xbf, w3tb, fctb, out);
    kM<<<dim3(B / 2, 8), 256, 0, stream>>>(xbf, Wcf, w3tb, fctb, out);
}